// Round 3
// baseline (2804.505 us; speedup 1.0000x reference)
//
#include <hip/hip_runtime.h>
#include <math.h>
#include <stdint.h>

#define HP 256
#define PTS 8                 // points per workgroup
#define ROWS 64               // 8 points x 8 channels (ch7 dummy)
#define ASTRIDE 260           // u32 per A row
#define NLAYER 6
#define WT_ELEMS (6*256*256)  // per hi/lo array, fp16

typedef _Float16 half8 __attribute__((ext_vector_type(8)));
typedef float   float4v __attribute__((ext_vector_type(4)));

// f32 extras section (float offsets within section)
#define C_WI 0                // [3][256]
#define C_BI 768              // [256]
#define C_BH 1024             // [6][256]
#define C_WO 2560             // [256][4]
#define C_TOT 3584

__device__ __forceinline__ float fast_tanh(float x) {
    float e = __expf(2.0f * x);
    return 1.0f - __fdividef(2.0f, e + 1.0f);
}

__device__ __forceinline__ uint32_t pack_hl(float x) {
    _Float16 h = (_Float16)x;
    float r = (x - (float)h) * 1024.0f;
    _Float16 l = (_Float16)r;
    union { _Float16 f; uint16_t u; } ch, cl;
    ch.f = h; cl.f = l;
    return (uint32_t)ch.u | ((uint32_t)cl.u << 16);
}

__device__ __forceinline__ float unpack_hl(uint32_t u) {
    union { uint16_t s; _Float16 h; } a, b;
    a.s = (uint16_t)(u & 0xffff); b.s = (uint16_t)(u >> 16);
    return (float)a.h + (float)b.h * (1.0f / 1024.0f);
}

// ---------------- prep: transpose + split weights ----------------
__global__ void prep_kernel(const float* __restrict__ W_in, const float* __restrict__ b_in,
                            const float* __restrict__ W_h,  const float* __restrict__ b_h,
                            const float* __restrict__ W_out, void* __restrict__ wsv)
{
    _Float16* wt_hi = (_Float16*)wsv;
    _Float16* wt_lo = wt_hi + WT_ELEMS;
    float* cf = (float*)((char*)wsv + (size_t)2 * WT_ELEMS * 2);

    int i0 = blockIdx.x * blockDim.x + threadIdx.x;
    int stride = gridDim.x * blockDim.x;
    for (int i = i0; i < WT_ELEMS; i += stride) {
        int l = i >> 16, n = (i >> 8) & 255, k = i & 255;
        float w = (n < 250 && k < 250) ? W_h[(l*250 + k)*250 + n] : 0.0f;  // Wt[l][n][k]
        _Float16 h = (_Float16)w;
        _Float16 lo = (_Float16)((w - (float)h) * 1024.0f);
        wt_hi[i] = h; wt_lo[i] = lo;
    }
    for (int i = i0; i < C_TOT; i += stride) {
        float v = 0.0f;
        if (i < C_BI) { int r = i >> 8, j = i & 255; if (j < 250) v = W_in[r*250 + j]; }
        else if (i < C_BH) { int j = i - C_BI; if (j < 250) v = b_in[j]; }
        else if (i < C_WO) { int idx = i - C_BH; int l = idx >> 8, j = idx & 255; if (j < 250) v = b_h[l*250 + j]; }
        else { int idx = i - C_WO; int k = idx >> 2, o = idx & 3; if (k < 250) v = W_out[k*4 + o]; }
        cf[i] = v;
    }
}

// ---------------- fused PINN kernel ----------------
// 512 threads = 8 waves: wave = (chh<<2) | rt ; rt: 16-row tile, chh: 128-col half
__launch_bounds__(512, 4)
__global__ void pinn_mfma(const float* __restrict__ xg, const float* __restrict__ yg,
                          const float* __restrict__ tg, const void* __restrict__ wsv,
                          const float* __restrict__ b_out, const float* __restrict__ act,
                          float* __restrict__ out, int N)
{
    __shared__ uint32_t Apack[ROWS * ASTRIDE];
    __shared__ float zo[PTS][28];

    const _Float16* __restrict__ wt_hi = (const _Float16*)wsv;
    const _Float16* __restrict__ wt_lo = wt_hi + WT_ELEMS;
    const float* __restrict__ cf = (const float*)((const char*)wsv + (size_t)2 * WT_ELEMS * 2);

    const int tid  = threadIdx.x;
    const int lane = tid & 63;
    const int wave = tid >> 6;
    const int rt   = wave & 3;        // row tile: rows 16*rt .. +15
    const int chh  = wave >> 2;       // col half: cols 128*chh .. +127
    const int q    = lane >> 4;       // quad
    const int j16  = lane & 15;

    // ---------- input layer jet: thread j = tid (<256) handles neuron j for all 8 points ----------
    if (tid < 256) {
        int j = tid;
        float wi0 = cf[C_WI + j], wi1 = cf[C_WI + 256 + j], wi2 = cf[C_WI + 512 + j];
        float biv = cf[C_BI + j];
        float c0 = 10.0f * act[0];
        #pragma unroll
        for (int p = 0; p < PTS; ++p) {
            int gp = blockIdx.x * PTS + p;
            gp = gp < N ? gp : N - 1;
            float px = xg[gp], py = yg[gp], pt = tg[gp];
            float z = px*wi0 + py*wi1 + pt*wi2 + biv;
            float y = fast_tanh(c0 * z);
            float s = 1.0f - y*y;
            float cs = c0 * s;
            float m2 = -2.0f * c0 * cs * y;
            uint32_t* r = &Apack[(8*p) * ASTRIDE + j];
            r[0*ASTRIDE] = pack_hl(y);
            r[1*ASTRIDE] = pack_hl(cs*wi0);
            r[2*ASTRIDE] = pack_hl(cs*wi1);
            r[3*ASTRIDE] = pack_hl(cs*wi2);
            r[4*ASTRIDE] = pack_hl(m2*wi0*wi0);
            r[5*ASTRIDE] = pack_hl(m2*wi1*wi1);
            r[6*ASTRIDE] = pack_hl(m2*wi0*wi1);
            r[7*ASTRIDE] = 0u;
        }
    }

    // ---------- hidden layers ----------
    for (int L = 0; L < NLAYER; ++L) {
        float cc = 10.0f * act[L + 1];
        __syncthreads();                       // Apack stable

        // load this wave's A fragments (1 row-tile x full K) into registers — once per layer
        half8 Ahi[8], Alo[8];
        #pragma unroll
        for (int s = 0; s < 8; ++s) {
            const uint32_t* src = &Apack[(16*rt + j16) * ASTRIDE + 32*s + 8*q];
            uint4 pa = *(const uint4*)(src);
            uint4 pb = *(const uint4*)(src + 4);
            union { uint32_t u[4]; half8 h; } uh, ul;
            uh.u[0] = (pa.x & 0xffffu) | (pa.y << 16);
            uh.u[1] = (pa.z & 0xffffu) | (pa.w << 16);
            uh.u[2] = (pb.x & 0xffffu) | (pb.y << 16);
            uh.u[3] = (pb.z & 0xffffu) | (pb.w << 16);
            ul.u[0] = (pa.x >> 16) | (pa.y & 0xffff0000u);
            ul.u[1] = (pa.z >> 16) | (pa.w & 0xffff0000u);
            ul.u[2] = (pb.x >> 16) | (pb.y & 0xffff0000u);
            ul.u[3] = (pb.z >> 16) | (pb.w & 0xffff0000u);
            Ahi[s] = uh.h;
            Alo[s] = ul.h;
        }
        __syncthreads();                       // all reads done before any overwrite

        const _Float16* __restrict__ wbase_hi = wt_hi + ((size_t)L << 16);
        const _Float16* __restrict__ wbase_lo = wt_lo + ((size_t)L << 16);

        for (int t = 0; t < 8; ++t) {
            int nrow = 128*chh + 16*t + j16;          // this lane's B row (out neuron n)
            const _Float16* bp_hi = wbase_hi + (size_t)nrow * 256 + 8*q;
            const _Float16* bp_lo = wbase_lo + (size_t)nrow * 256 + 8*q;

            float4v m  = {0.f,0.f,0.f,0.f};
            float4v ch = {0.f,0.f,0.f,0.f};   // Ahi * Blo
            float4v cl = {0.f,0.f,0.f,0.f};   // Alo * Bhi
            #pragma unroll
            for (int s = 0; s < 8; ++s) {
                half8 bh = *(const half8*)(bp_hi + 32*s);
                half8 bl = *(const half8*)(bp_lo + 32*s);
                m  = __builtin_amdgcn_mfma_f32_16x16x32_f16(Ahi[s], bh, m,  0, 0, 0);
                ch = __builtin_amdgcn_mfma_f32_16x16x32_f16(Ahi[s], bl, ch, 0, 0, 0);
                cl = __builtin_amdgcn_mfma_f32_16x16x32_f16(Alo[s], bh, cl, 0, 0, 0);
            }
            float4v z4;
            #pragma unroll
            for (int i = 0; i < 4; ++i)
                z4[i] = m[i] + (ch[i] + cl[i]) * (1.0f/1024.0f);

            // ---- epilogue: jet activation, write next A in place ----
            {
                int pl = q >> 1, ql = q & 1;
                float e0 = __shfl_xor(z4[0], 16);
                float e1 = __shfl_xor(z4[1], 16);
                float e2 = __shfl_xor(z4[2], 16);
                float z  = ql ? e0 : z4[0];
                float y  = fast_tanh(cc * z);
                float sh = 1.0f - y*y;
                float cs = cc * sh;
                float o0, o1, o2, o3;
                if (!ql) {
                    o0 = y; o1 = cs*z4[1]; o2 = cs*z4[2]; o3 = cs*z4[3];
                } else {
                    float m2c = -2.0f * cc * cs * y;
                    o0 = cs*z4[0] + m2c*e1*e1;   // ch4: cs*zxx + m2*zx^2
                    o1 = cs*z4[1] + m2c*e2*e2;   // ch5
                    o2 = cs*z4[2] + m2c*e1*e2;   // ch6
                    o3 = 0.0f;                   // ch7 dummy
                }
                uint32_t* dst = &Apack[(16*rt + 8*pl + 4*ql) * ASTRIDE + 128*chh + 16*t + j16];
                dst[0*ASTRIDE] = pack_hl(o0);
                dst[1*ASTRIDE] = pack_hl(o1);
                dst[2*ASTRIDE] = pack_hl(o2);
                dst[3*ASTRIDE] = ql ? 0u : pack_hl(o3);
            }
        }
    }

    // ---------- output layer: 28 dots per point ----------
    __syncthreads();
    if (tid < PTS * 28) {
        int p = tid / 28, idx = tid % 28;
        int c = idx >> 2, o = idx & 3;
        const uint32_t* row = &Apack[(8*p + c) * ASTRIDE];
        float s = 0.0f;
        for (int k = 0; k < HP; ++k)
            s += unpack_hl(row[k]) * cf[C_WO + 4*k + o];
        zo[p][idx] = s;
    }
    __syncthreads();

    // ---------- heads + PDE residuals ----------
    if (tid < PTS) {
        int gp = blockIdx.x * PTS + tid;
        if (gp < N) {
            float zc[7][4];
            #pragma unroll
            for (int c = 0; c < 7; ++c)
                #pragma unroll
                for (int o = 0; o < 4; ++o)
                    zc[c][o] = zo[tid][c*4 + o] + (c == 0 ? b_out[o] : 0.0f);

            float u  = zc[0][0], vv = zc[0][1];
            float u_x = zc[1][0], u_y = zc[2][0], u_t = zc[3][0];
            float u_xx = zc[4][0], u_yy = zc[5][0];
            float v_x = zc[1][1], v_y = zc[2][1], v_t = zc[3][1];
            float v_xx = zc[4][1], v_yy = zc[5][1];

            float ep  = expf(zc[0][2]);
            float p_x = ep * zc[1][2], p_y = ep * zc[2][2];

            float a   = 1.0f / (1.0f + expf(-zc[0][3]));
            float sp  = a * (1.0f - a);
            float spp = sp * (1.0f - 2.0f*a);
            float z1a = zc[1][3], z2a = zc[2][3];
            float a_x = sp * z1a, a_y = sp * z2a, a_t = sp * zc[3][3];
            float a_xx = spp*z1a*z1a + sp*zc[4][3];
            float a_yy = spp*z2a*z2a + sp*zc[5][3];
            float a_xy = spp*z1a*z2a + sp*zc[6][3];

            float mu_x = -9.0f*a_x, mu_y = -9.0f*a_y;
            float mu   = 10.0f - 9.0f*a;
            float rr   = 1.0f - 0.9f*a;
            float g  = sqrtf(a_x*a_x + a_y*a_y + 2.220446049250313e-16f);
            float g3 = g*g*g;
            float curv = -((a_xx + a_yy)/g
                         - (a_x*a_x*a_xx + a_y*a_y*a_yy + 2.0f*a_x*a_y*a_xy)/g3);
            float one_Re   = mu   * 0.002f;
            float one_Re_x = mu_x * 0.002f;
            float one_Re_y = mu_y * 0.002f;

            float PDE_m = u_x + v_y;
            float PDE_a = a_t + u*a_x + vv*a_y;
            float PDE_u = (u_t + u*u_x + vv*u_y)*rr + p_x - 0.049f*curv*a_x
                        - one_Re*(u_xx + u_yy) - 2.0f*one_Re_x*u_x - one_Re_y*(u_y + v_x);
            float PDE_v = (v_t + u*v_x + vv*v_y)*rr + p_y - 0.049f*curv*a_y
                        - one_Re*(v_xx + v_yy) - rr*0.49f
                        - 2.0f*one_Re_y*v_y - one_Re_x*(u_y + v_x);

            out[0*N + gp] = PDE_m;
            out[1*N + gp] = PDE_u;
            out[2*N + gp] = PDE_v;
            out[3*N + gp] = PDE_a;
        }
    }
}

extern "C" void kernel_launch(void* const* d_in, const int* in_sizes, int n_in,
                              void* d_out, int out_size, void* d_ws, size_t ws_size,
                              hipStream_t stream)
{
    const float* x     = (const float*)d_in[0];
    const float* y     = (const float*)d_in[1];
    const float* t     = (const float*)d_in[2];
    const float* W_in  = (const float*)d_in[3];
    const float* b_in  = (const float*)d_in[4];
    const float* W_h   = (const float*)d_in[5];
    const float* b_h   = (const float*)d_in[6];
    const float* W_out = (const float*)d_in[7];
    const float* b_out = (const float*)d_in[8];
    const float* act   = (const float*)d_in[9];
    float* out = (float*)d_out;
    int N = in_sizes[0];

    hipLaunchKernelGGL(prep_kernel, dim3(512), dim3(256), 0, stream,
                       W_in, b_in, W_h, b_h, W_out, d_ws);
    int nb = (N + PTS - 1) / PTS;
    hipLaunchKernelGGL(pinn_mfma, dim3(nb), dim3(512), 0, stream,
                       x, y, t, d_ws, b_out, act, out, N);
}

// Round 4
// 1002.217 us; speedup vs baseline: 2.7983x; 2.7983x over previous
//
#include <hip/hip_runtime.h>
#include <math.h>
#include <stdint.h>

#define HP 256
#define PTS 8                 // points per workgroup
#define ROWS 64               // 8 points x 8 channels (ch7 dummy)
#define ASTRIDE 260           // u32 per A row
#define NLAYER 6
#define WT_ELEMS (6*256*256)  // per hi/lo array, fp16

typedef _Float16 half8 __attribute__((ext_vector_type(8)));
typedef float  float16v __attribute__((ext_vector_type(16)));

// f32 extras section (float offsets within section)
#define C_WI 0                // [3][256]
#define C_BI 768              // [256]
#define C_BH 1024             // [6][256]
#define C_WO 2560             // [256][4]
#define C_TOT 3584

__device__ __forceinline__ float fast_tanh(float x) {
    float e = __expf(2.0f * x);
    return 1.0f - __fdividef(2.0f, e + 1.0f);
}

__device__ __forceinline__ uint32_t pack_hl(float x) {
    _Float16 h = (_Float16)x;
    float r = (x - (float)h) * 1024.0f;
    _Float16 l = (_Float16)r;
    union { _Float16 f; uint16_t u; } ch, cl;
    ch.f = h; cl.f = l;
    return (uint32_t)ch.u | ((uint32_t)cl.u << 16);
}

__device__ __forceinline__ float unpack_hl(uint32_t u) {
    union { uint16_t s; _Float16 h; } a, b;
    a.s = (uint16_t)(u & 0xffff); b.s = (uint16_t)(u >> 16);
    return (float)a.h + (float)b.h * (1.0f / 1024.0f);
}

__device__ __forceinline__ float16v zero16() {
    float16v z;
    #pragma unroll
    for (int i = 0; i < 16; ++i) z[i] = 0.0f;
    return z;
}

// unpack 8 packed u32 (hi|lo per element) -> half8 hi, half8 lo
__device__ __forceinline__ void unpack8(uint4 pa, uint4 pb, half8* hi, half8* lo) {
    union { uint32_t u[4]; half8 h; } uh, ul;
    uh.u[0] = (pa.x & 0xffffu) | (pa.y << 16);
    uh.u[1] = (pa.z & 0xffffu) | (pa.w << 16);
    uh.u[2] = (pb.x & 0xffffu) | (pb.y << 16);
    uh.u[3] = (pb.z & 0xffffu) | (pb.w << 16);
    ul.u[0] = (pa.x >> 16) | (pa.y & 0xffff0000u);
    ul.u[1] = (pa.z >> 16) | (pa.w & 0xffff0000u);
    ul.u[2] = (pb.x >> 16) | (pb.y & 0xffff0000u);
    ul.u[3] = (pb.z >> 16) | (pb.w & 0xffff0000u);
    *hi = uh.h; *lo = ul.h;
}

// ---------------- prep: transpose + split weights ----------------
__global__ void prep_kernel(const float* __restrict__ W_in, const float* __restrict__ b_in,
                            const float* __restrict__ W_h,  const float* __restrict__ b_h,
                            const float* __restrict__ W_out, void* __restrict__ wsv)
{
    _Float16* wt_hi = (_Float16*)wsv;
    _Float16* wt_lo = wt_hi + WT_ELEMS;
    float* cf = (float*)((char*)wsv + (size_t)2 * WT_ELEMS * 2);

    int i0 = blockIdx.x * blockDim.x + threadIdx.x;
    int stride = gridDim.x * blockDim.x;
    for (int i = i0; i < WT_ELEMS; i += stride) {
        int l = i >> 16, n = (i >> 8) & 255, k = i & 255;
        float w = (n < 250 && k < 250) ? W_h[(l*250 + k)*250 + n] : 0.0f;  // Wt[l][n][k]
        _Float16 h = (_Float16)w;
        _Float16 lo = (_Float16)((w - (float)h) * 1024.0f);
        wt_hi[i] = h; wt_lo[i] = lo;
    }
    for (int i = i0; i < C_TOT; i += stride) {
        float v = 0.0f;
        if (i < C_BI) { int r = i >> 8, j = i & 255; if (j < 250) v = W_in[r*250 + j]; }
        else if (i < C_BH) { int j = i - C_BI; if (j < 250) v = b_in[j]; }
        else if (i < C_WO) { int idx = i - C_BH; int l = idx >> 8, j = idx & 255; if (j < 250) v = b_h[l*250 + j]; }
        else { int idx = i - C_WO; int k = idx >> 2, o = idx & 3; if (k < 250) v = W_out[k*4 + o]; }
        cf[i] = v;
    }
}

// ---------------- fused PINN kernel ----------------
// 256 threads = 4 waves. Wave w owns cols 64*w..64*w+63 (two 32-col subtiles t=0,1)
// and ALL 64 rows (two 32-row tiles rt=0,1). MFMA 32x32x16 f16, 2-chain hi/lo comp.
__launch_bounds__(256, 2)
__global__ void pinn_mfma(const float* __restrict__ xg, const float* __restrict__ yg,
                          const float* __restrict__ tg, const void* __restrict__ wsv,
                          const float* __restrict__ b_out, const float* __restrict__ act,
                          float* __restrict__ out, int N)
{
    __shared__ uint32_t Apack[ROWS * ASTRIDE];
    __shared__ float zo[PTS][28];

    const _Float16* __restrict__ wt_hi = (const _Float16*)wsv;
    const _Float16* __restrict__ wt_lo = wt_hi + WT_ELEMS;
    const float* __restrict__ cf = (const float*)((const char*)wsv + (size_t)2 * WT_ELEMS * 2);

    const int tid  = threadIdx.x;
    const int lane = tid & 63;
    const int qtr  = tid >> 6;        // col quarter: 64*qtr
    const int lo5  = lane & 31;
    const int hi5  = lane >> 5;

    // ---------- input layer jet: thread j = tid handles neuron j for all 8 points ----------
    {
        int j = tid;
        float wi0 = cf[C_WI + j], wi1 = cf[C_WI + 256 + j], wi2 = cf[C_WI + 512 + j];
        float biv = cf[C_BI + j];
        float c0 = 10.0f * act[0];
        #pragma unroll
        for (int p = 0; p < PTS; ++p) {
            int gp = blockIdx.x * PTS + p;
            gp = gp < N ? gp : N - 1;
            float px = xg[gp], py = yg[gp], pt = tg[gp];
            float z = px*wi0 + py*wi1 + pt*wi2 + biv;
            float y = fast_tanh(c0 * z);
            float s = 1.0f - y*y;
            float cs = c0 * s;
            float m2 = -2.0f * c0 * cs * y;
            uint32_t* r = &Apack[(8*p) * ASTRIDE + j];
            r[0*ASTRIDE] = pack_hl(y);
            r[1*ASTRIDE] = pack_hl(cs*wi0);
            r[2*ASTRIDE] = pack_hl(cs*wi1);
            r[3*ASTRIDE] = pack_hl(cs*wi2);
            r[4*ASTRIDE] = pack_hl(m2*wi0*wi0);
            r[5*ASTRIDE] = pack_hl(m2*wi1*wi1);
            r[6*ASTRIDE] = pack_hl(m2*wi0*wi1);
            r[7*ASTRIDE] = 0u;
        }
    }

    // ---------- hidden layers ----------
    for (int L = 0; L < NLAYER; ++L) {
        float cc = 10.0f * act[L + 1];
        const _Float16* __restrict__ wbh = wt_hi + ((size_t)L << 16);
        const _Float16* __restrict__ wbl = wt_lo + ((size_t)L << 16);

        const int n0 = 64*qtr + lo5;                  // t=0 output neuron
        const _Float16* ph0 = wbh + (size_t)n0 * 256 + 8*hi5;
        const _Float16* pl0 = wbl + (size_t)n0 * 256 + 8*hi5;
        const _Float16* ph1 = ph0 + 32 * 256;         // t=1: n0+32
        const _Float16* pl1 = pl0 + 32 * 256;

        float16v m00 = zero16(), m01 = zero16(), m10 = zero16(), m11 = zero16();
        float16v c00 = zero16(), c01 = zero16(), c10 = zero16(), c11 = zero16();

        __syncthreads();                              // Apack stable (prev writes done)

        half8 Bh0 = *(const half8*)(ph0);
        half8 Bl0 = *(const half8*)(pl0);
        half8 Bh1 = *(const half8*)(ph1);
        half8 Bl1 = *(const half8*)(pl1);

        #pragma unroll 2
        for (int s = 0; s < 16; ++s) {
            int so = 16 * ((s + 1) & 15);             // prefetch offset (s=15 redundant, harmless)
            half8 nBh0 = *(const half8*)(ph0 + so);
            half8 nBl0 = *(const half8*)(pl0 + so);
            half8 nBh1 = *(const half8*)(ph1 + so);
            half8 nBl1 = *(const half8*)(pl1 + so);

            const uint32_t* a0 = &Apack[lo5 * ASTRIDE + 16*s + 8*hi5];
            const uint32_t* a1 = a0 + 32 * ASTRIDE;
            uint4 p0a = *(const uint4*)a0, p0b = *(const uint4*)(a0 + 4);
            uint4 p1a = *(const uint4*)a1, p1b = *(const uint4*)(a1 + 4);
            half8 A0h, A0l, A1h, A1l;
            unpack8(p0a, p0b, &A0h, &A0l);
            unpack8(p1a, p1b, &A1h, &A1l);

            m00 = __builtin_amdgcn_mfma_f32_32x32x16_f16(A0h, Bh0, m00, 0, 0, 0);
            m01 = __builtin_amdgcn_mfma_f32_32x32x16_f16(A1h, Bh0, m01, 0, 0, 0);
            m10 = __builtin_amdgcn_mfma_f32_32x32x16_f16(A0h, Bh1, m10, 0, 0, 0);
            m11 = __builtin_amdgcn_mfma_f32_32x32x16_f16(A1h, Bh1, m11, 0, 0, 0);
            c00 = __builtin_amdgcn_mfma_f32_32x32x16_f16(A0h, Bl0, c00, 0, 0, 0);
            c01 = __builtin_amdgcn_mfma_f32_32x32x16_f16(A1h, Bl0, c01, 0, 0, 0);
            c10 = __builtin_amdgcn_mfma_f32_32x32x16_f16(A0h, Bl1, c10, 0, 0, 0);
            c11 = __builtin_amdgcn_mfma_f32_32x32x16_f16(A1h, Bl1, c11, 0, 0, 0);
            c00 = __builtin_amdgcn_mfma_f32_32x32x16_f16(A0l, Bh0, c00, 0, 0, 0);
            c01 = __builtin_amdgcn_mfma_f32_32x32x16_f16(A1l, Bh0, c01, 0, 0, 0);
            c10 = __builtin_amdgcn_mfma_f32_32x32x16_f16(A0l, Bh1, c10, 0, 0, 0);
            c11 = __builtin_amdgcn_mfma_f32_32x32x16_f16(A1l, Bh1, c11, 0, 0, 0);

            Bh0 = nBh0; Bl0 = nBl0; Bh1 = nBh1; Bl1 = nBl1;
        }

        __syncthreads();                              // all reads done before any overwrite

        float bb0 = cf[C_BH + (L << 8) + n0];         // hidden bias (zeros in practice)
        float bb1 = cf[C_BH + (L << 8) + n0 + 32];

        #pragma unroll
        for (int t = 0; t < 2; ++t) {
            float bb = t ? bb1 : bb0;
            int ncol = 64*qtr + 32*t + lo5;
            #pragma unroll
            for (int rt = 0; rt < 2; ++rt) {
                float16v mv = t ? (rt ? m11 : m10) : (rt ? m01 : m00);
                float16v cv = t ? (rt ? c11 : c10) : (rt ? c01 : c00);
                #pragma unroll
                for (int p = 0; p < 4; ++p) {
                    float za = mv[4*p+0] + cv[4*p+0] * (1.0f/1024.0f);
                    float zb = mv[4*p+1] + cv[4*p+1] * (1.0f/1024.0f);
                    float zc_ = mv[4*p+2] + cv[4*p+2] * (1.0f/1024.0f);
                    float zd = mv[4*p+3] + cv[4*p+3] * (1.0f/1024.0f);
                    if (!hi5) za += bb;               // bias on value channel
                    float e0 = __shfl_xor(za, 32);
                    float e1 = __shfl_xor(zb, 32);
                    float e2 = __shfl_xor(zc_, 32);
                    float zval = hi5 ? e0 : za;
                    float y  = fast_tanh(cc * zval);
                    float sh = 1.0f - y*y;
                    float cs = cc * sh;
                    float o0, o1, o2, o3;
                    if (!hi5) {
                        o0 = y; o1 = cs*zb; o2 = cs*zc_; o3 = cs*zd;
                    } else {
                        float m2c = -2.0f * cc * cs * y;
                        float zx = e1, zy = e2;
                        o0 = cs*za  + m2c*zx*zx;      // ch4
                        o1 = cs*zb  + m2c*zy*zy;      // ch5
                        o2 = cs*zc_ + m2c*zx*zy;      // ch6
                        o3 = 0.0f;                    // ch7 dummy
                    }
                    uint32_t* dst = &Apack[(32*rt + 8*p + 4*hi5) * ASTRIDE + ncol];
                    dst[0*ASTRIDE] = pack_hl(o0);
                    dst[1*ASTRIDE] = pack_hl(o1);
                    dst[2*ASTRIDE] = pack_hl(o2);
                    dst[3*ASTRIDE] = hi5 ? 0u : pack_hl(o3);
                }
            }
        }
    }

    // ---------- output layer: 28 dots per point ----------
    __syncthreads();
    if (tid < PTS * 28) {
        int p = tid / 28, idx = tid % 28;
        int c = idx >> 2, o = idx & 3;
        const uint32_t* row = &Apack[(8*p + c) * ASTRIDE];
        float s = 0.0f;
        for (int k = 0; k < HP; ++k)
            s += unpack_hl(row[k]) * cf[C_WO + 4*k + o];
        zo[p][idx] = s;
    }
    __syncthreads();

    // ---------- heads + PDE residuals ----------
    if (tid < PTS) {
        int gp = blockIdx.x * PTS + tid;
        if (gp < N) {
            float zc[7][4];
            #pragma unroll
            for (int c = 0; c < 7; ++c)
                #pragma unroll
                for (int o = 0; o < 4; ++o)
                    zc[c][o] = zo[tid][c*4 + o] + (c == 0 ? b_out[o] : 0.0f);

            float u  = zc[0][0], vv = zc[0][1];
            float u_x = zc[1][0], u_y = zc[2][0], u_t = zc[3][0];
            float u_xx = zc[4][0], u_yy = zc[5][0];
            float v_x = zc[1][1], v_y = zc[2][1], v_t = zc[3][1];
            float v_xx = zc[4][1], v_yy = zc[5][1];

            float ep  = expf(zc[0][2]);
            float p_x = ep * zc[1][2], p_y = ep * zc[2][2];

            float a   = 1.0f / (1.0f + expf(-zc[0][3]));
            float sp  = a * (1.0f - a);
            float spp = sp * (1.0f - 2.0f*a);
            float z1a = zc[1][3], z2a = zc[2][3];
            float a_x = sp * z1a, a_y = sp * z2a, a_t = sp * zc[3][3];
            float a_xx = spp*z1a*z1a + sp*zc[4][3];
            float a_yy = spp*z2a*z2a + sp*zc[5][3];
            float a_xy = spp*z1a*z2a + sp*zc[6][3];

            float mu_x = -9.0f*a_x, mu_y = -9.0f*a_y;
            float mu   = 10.0f - 9.0f*a;
            float rr   = 1.0f - 0.9f*a;
            float g  = sqrtf(a_x*a_x + a_y*a_y + 2.220446049250313e-16f);
            float g3 = g*g*g;
            float curv = -((a_xx + a_yy)/g
                         - (a_x*a_x*a_xx + a_y*a_y*a_yy + 2.0f*a_x*a_y*a_xy)/g3);
            float one_Re   = mu   * 0.002f;
            float one_Re_x = mu_x * 0.002f;
            float one_Re_y = mu_y * 0.002f;

            float PDE_m = u_x + v_y;
            float PDE_a = a_t + u*a_x + vv*a_y;
            float PDE_u = (u_t + u*u_x + vv*u_y)*rr + p_x - 0.049f*curv*a_x
                        - one_Re*(u_xx + u_yy) - 2.0f*one_Re_x*u_x - one_Re_y*(u_y + v_x);
            float PDE_v = (v_t + u*v_x + vv*v_y)*rr + p_y - 0.049f*curv*a_y
                        - one_Re*(v_xx + v_yy) - rr*0.49f
                        - 2.0f*one_Re_y*v_y - one_Re_x*(u_y + v_x);

            out[0*N + gp] = PDE_m;
            out[1*N + gp] = PDE_u;
            out[2*N + gp] = PDE_v;
            out[3*N + gp] = PDE_a;
        }
    }
}

extern "C" void kernel_launch(void* const* d_in, const int* in_sizes, int n_in,
                              void* d_out, int out_size, void* d_ws, size_t ws_size,
                              hipStream_t stream)
{
    const float* x     = (const float*)d_in[0];
    const float* y     = (const float*)d_in[1];
    const float* t     = (const float*)d_in[2];
    const float* W_in  = (const float*)d_in[3];
    const float* b_in  = (const float*)d_in[4];
    const float* W_h   = (const float*)d_in[5];
    const float* b_h   = (const float*)d_in[6];
    const float* W_out = (const float*)d_in[7];
    const float* b_out = (const float*)d_in[8];
    const float* act   = (const float*)d_in[9];
    float* out = (float*)d_out;
    int N = in_sizes[0];

    hipLaunchKernelGGL(prep_kernel, dim3(512), dim3(256), 0, stream,
                       W_in, b_in, W_h, b_h, W_out, d_ws);
    int nb = (N + PTS - 1) / PTS;
    hipLaunchKernelGGL(pinn_mfma, dim3(nb), dim3(256), 0, stream,
                       x, y, t, d_ws, b_out, act, out, N);
}